// Round 1
// baseline (13449.608 us; speedup 1.0000x reference)
//
#include <hip/hip_runtime.h>
#include <math.h>

#define SQ 1024      // sequence length S
#define ED 1024      // embed dim E
#define NH 16        // heads
#define HD 64        // head dim
#define NL 12        // layers
#define ID 4096      // MLP inner dim
#define NV 50257     // vocab
#define EPS 1e-5f

// ---------------- embedding: h[s][e] = wte[ids[s]][e] + wpe[s][e] ----------------
__global__ void embed_kernel(const int* __restrict__ ids, const float* __restrict__ wte,
                             const float* __restrict__ wpe, float* __restrict__ h) {
    int s = blockIdx.x;
    int tok = ids[s];
    for (int e = threadIdx.x; e < ED; e += 256)
        h[(size_t)s * ED + e] = wte[(size_t)tok * ED + e] + wpe[(size_t)s * ED + e];
}

// ---------------- layernorm: one block per row ----------------
__global__ void ln_kernel(const float* __restrict__ in, const float* __restrict__ g,
                          const float* __restrict__ b, float* __restrict__ out) {
    int s = blockIdx.x;
    int tid = threadIdx.x;
    const float* row = in + (size_t)s * ED;
    __shared__ float red[256];
    float sum = 0.f;
    for (int e = tid; e < ED; e += 256) sum += row[e];
    red[tid] = sum; __syncthreads();
    for (int off = 128; off > 0; off >>= 1) { if (tid < off) red[tid] += red[tid + off]; __syncthreads(); }
    float mu = red[0] * (1.f / ED);
    __syncthreads();
    float vs = 0.f;
    for (int e = tid; e < ED; e += 256) { float d = row[e] - mu; vs += d * d; }
    red[tid] = vs; __syncthreads();
    for (int off = 128; off > 0; off >>= 1) { if (tid < off) red[tid] += red[tid + off]; __syncthreads(); }
    float rstd = rsqrtf(red[0] * (1.f / ED) + EPS);
    for (int e = tid; e < ED; e += 256)
        out[(size_t)s * ED + e] = (row[e] - mu) * rstd * g[e] + b[e];
}

// ---------------- tiled f32 GEMM: C[M,N] = act(A[M,K] @ Wt[N,K]^T + bias) (+ res) ----------------
// 64x64 tile, BK=16, 256 threads, 4x4 per thread.
template <int ACT, bool RES>
__global__ void gemm_kernel(const float* __restrict__ A, const float* __restrict__ Wt,
                            const float* __restrict__ bias, const float* __restrict__ res,
                            float* __restrict__ C, int M, int N, int K) {
    __shared__ float As[16][68];
    __shared__ float Bs[16][68];
    int tid = threadIdx.x;
    int m0 = blockIdx.y * 64, n0 = blockIdx.x * 64;
    int tx = tid & 15, ty = tid >> 4;
    float acc[4][4] = {};
    int lr = tid >> 2;            // 0..63 row within tile
    int lk = (tid & 3) * 4;       // 0,4,8,12 k within tile
    for (int k0 = 0; k0 < K; k0 += 16) {
        float4 av = *(const float4*)(A + (size_t)(m0 + lr) * K + k0 + lk);
        As[lk][lr] = av.x; As[lk + 1][lr] = av.y; As[lk + 2][lr] = av.z; As[lk + 3][lr] = av.w;
        float4 bv = *(const float4*)(Wt + (size_t)(n0 + lr) * K + k0 + lk);
        Bs[lk][lr] = bv.x; Bs[lk + 1][lr] = bv.y; Bs[lk + 2][lr] = bv.z; Bs[lk + 3][lr] = bv.w;
        __syncthreads();
#pragma unroll
        for (int kk = 0; kk < 16; ++kk) {
            float a[4], bb[4];
#pragma unroll
            for (int i = 0; i < 4; ++i) a[i] = As[kk][ty * 4 + i];
#pragma unroll
            for (int j = 0; j < 4; ++j) bb[j] = Bs[kk][tx * 4 + j];
#pragma unroll
            for (int i = 0; i < 4; ++i)
#pragma unroll
                for (int j = 0; j < 4; ++j) acc[i][j] = fmaf(a[i], bb[j], acc[i][j]);
        }
        __syncthreads();
    }
#pragma unroll
    for (int i = 0; i < 4; ++i) {
        int row = m0 + ty * 4 + i;
#pragma unroll
        for (int j = 0; j < 4; ++j) {
            int col = n0 + tx * 4 + j;
            float v = acc[i][j] + bias[col];
            if (ACT == 1) {  // gelu_new
                float x = v;
                v = 0.5f * x * (1.f + tanhf(0.7978845608028654f * (x + 0.044715f * x * x * x)));
            }
            if (RES) v += res[(size_t)row * N + col];
            C[(size_t)row * N + col] = v;
        }
    }
}

// ---------------- kv cache copy: qkv[s][E+c] -> kc[(h*S+s)*64+d] ----------------
__global__ void kvcopy_kernel(const float* __restrict__ qkv, float* __restrict__ kc,
                              float* __restrict__ vc) {
    int idx = blockIdx.x * 256 + threadIdx.x;  // over S*E
    int s = idx >> 10, c = idx & 1023;
    int hh = c >> 6, d = c & 63;
    size_t o = ((size_t)hh * SQ + s) * HD + d;
    kc[o] = qkv[(size_t)s * 3 * ED + ED + c];
    vc[o] = qkv[(size_t)s * 3 * ED + 2 * ED + c];
}

// ---------------- attention: one block per (q row, head) ----------------
__global__ void attn_kernel(const float* __restrict__ qkv, const float* __restrict__ kc,
                            const float* __restrict__ vc, const float* __restrict__ ab,
                            float* __restrict__ ctx) {
    int q = blockIdx.x, hh = blockIdx.y;
    int tid = threadIdx.x;
    __shared__ float qs[HD];
    __shared__ float sc[SQ];
    __shared__ float red[256];
    if (tid < HD) qs[tid] = qkv[(size_t)q * 3 * ED + hh * HD + tid];
    __syncthreads();
    float lmax = -1e30f;
    for (int k = tid; k <= q; k += 256) {
        const float* kr = kc + ((size_t)hh * SQ + k) * HD;
        float dot = 0.f;
#pragma unroll
        for (int d = 0; d < HD; ++d) dot = fmaf(qs[d], kr[d], dot);
        float v = dot * 0.125f + ab[(size_t)q * SQ + k];
        sc[k] = v;
        lmax = fmaxf(lmax, v);
    }
    red[tid] = lmax; __syncthreads();
    for (int off = 128; off > 0; off >>= 1) { if (tid < off) red[tid] = fmaxf(red[tid], red[tid + off]); __syncthreads(); }
    float mx = red[0];
    __syncthreads();
    float lsum = 0.f;
    for (int k = tid; k <= q; k += 256) { float e = expf(sc[k] - mx); sc[k] = e; lsum += e; }
    red[tid] = lsum; __syncthreads();
    for (int off = 128; off > 0; off >>= 1) { if (tid < off) red[tid] += red[tid + off]; __syncthreads(); }
    float inv = 1.f / red[0];
    __syncthreads();
    int d = tid & 63, grp = tid >> 6;
    float acc = 0.f;
    for (int k = grp; k <= q; k += 4)
        acc = fmaf(sc[k], vc[((size_t)hh * SQ + k) * HD + d], acc);
    red[tid] = acc; __syncthreads();
    if (tid < 64) {
        float c = red[tid] + red[tid + 64] + red[tid + 128] + red[tid + 192];
        ctx[(size_t)q * ED + hh * HD + d] = c * inv;
    }
}

// ---------------- lm head matvec: logits[v] = x[S-1] . wte[v] ----------------
__global__ void lmhead_kernel(const float* __restrict__ x, const float* __restrict__ wte,
                              float* __restrict__ logits) {
    __shared__ float xs[ED];
    int tid = threadIdx.x;
    for (int i = tid; i < ED; i += 256) xs[i] = x[(size_t)(SQ - 1) * ED + i];
    __syncthreads();
    int wave = tid >> 6, lane = tid & 63;
    int v = blockIdx.x * 4 + wave;
    if (v >= NV) return;
    const float* wr = wte + (size_t)v * ED;
    float acc = 0.f;
#pragma unroll 4
    for (int t = 0; t < ED / 64; ++t) acc = fmaf(xs[lane + t * 64], wr[lane + t * 64], acc);
    for (int off = 32; off > 0; off >>= 1) acc += __shfl_down(acc, off, 64);
    if (lane == 0) logits[v] = acc;
}

// ---------------- softmax + argmax over V ----------------
__global__ void probs_kernel(const float* __restrict__ logits, float* __restrict__ out) {
    __shared__ float red[256];
    __shared__ int redi[256];
    int tid = threadIdx.x;
    float lmax = -1e30f; int li = 0;
    for (int v = tid; v < NV; v += 256) {
        float x = logits[v];
        if (x > lmax) { lmax = x; li = v; }
    }
    red[tid] = lmax; redi[tid] = li; __syncthreads();
    for (int off = 128; off > 0; off >>= 1) {
        if (tid < off) {
            float a = red[tid], b = red[tid + off];
            if (b > a || (b == a && redi[tid + off] < redi[tid])) { red[tid] = b; redi[tid] = redi[tid + off]; }
        }
        __syncthreads();
    }
    float mx = red[0]; int amax = redi[0];
    __syncthreads();
    float lsum = 0.f;
    for (int v = tid; v < NV; v += 256) lsum += expf(logits[v] - mx);
    red[tid] = lsum; __syncthreads();
    for (int off = 128; off > 0; off >>= 1) { if (tid < off) red[tid] += red[tid + off]; __syncthreads(); }
    float inv = 1.f / red[0];
    for (int v = tid; v < NV; v += 256) out[1 + v] = expf(logits[v] - mx) * inv;
    if (tid == 0) out[0] = (float)amax;
}

extern "C" void kernel_launch(void* const* d_in, const int* in_sizes, int n_in,
                              void* d_out, int out_size, void* d_ws, size_t ws_size,
                              hipStream_t stream) {
    const int*   ids      = (const int*)d_in[0];
    const float* wte      = (const float*)d_in[1];
    const float* wpe      = (const float*)d_in[2];
    const float* ln1_g    = (const float*)d_in[3];
    const float* ln1_b    = (const float*)d_in[4];
    const float* c_attn_w = (const float*)d_in[5];
    const float* c_attn_b = (const float*)d_in[6];
    const float* ab       = (const float*)d_in[7];
    const float* apw      = (const float*)d_in[8];
    const float* apb      = (const float*)d_in[9];
    const float* ln2_g    = (const float*)d_in[10];
    const float* ln2_b    = (const float*)d_in[11];
    const float* cfc_w    = (const float*)d_in[12];
    const float* cfc_b    = (const float*)d_in[13];
    const float* mpw      = (const float*)d_in[14];
    const float* mpb      = (const float*)d_in[15];
    const float* lnf_g    = (const float*)d_in[16];
    const float* lnf_b    = (const float*)d_in[17];

    float* out   = (float*)d_out;
    float* kc    = out + 1 + NV;                         // [L,H,S,HD]
    float* vc    = kc + (size_t)NL * NH * SQ * HD;

    float* ws    = (float*)d_ws;
    float* h     = ws;                                   // S*E
    float* x     = h + (size_t)SQ * ED;                  // S*E
    float* qkv   = x + (size_t)SQ * ED;                  // S*3E
    float* ctx   = qkv + (size_t)SQ * 3 * ED;            // S*E
    float* mbuf  = qkv;                                  // S*I (reuses qkv+ctx region, 16MB)
    float* logit = ctx + (size_t)SQ * ED;                // V

    embed_kernel<<<SQ, 256, 0, stream>>>(ids, wte, wpe, h);

    for (int l = 0; l < NL; ++l) {
        const size_t lEE = (size_t)l * ED * ED;
        float* kcl = kc + (size_t)l * NH * SQ * HD;
        float* vcl = vc + (size_t)l * NH * SQ * HD;

        ln_kernel<<<SQ, 256, 0, stream>>>(h, ln1_g + l * ED, ln1_b + l * ED, x);
        gemm_kernel<0, false><<<dim3(3 * ED / 64, SQ / 64), 256, 0, stream>>>(
            x, c_attn_w + 3 * lEE, c_attn_b + (size_t)l * 3 * ED, nullptr, qkv, SQ, 3 * ED, ED);
        kvcopy_kernel<<<SQ * ED / 256, 256, 0, stream>>>(qkv, kcl, vcl);
        attn_kernel<<<dim3(SQ, NH), 256, 0, stream>>>(qkv, kcl, vcl,
            ab + (size_t)l * SQ * SQ, ctx);
        gemm_kernel<0, true><<<dim3(ED / 64, SQ / 64), 256, 0, stream>>>(
            ctx, apw + lEE, apb + (size_t)l * ED, h, h, SQ, ED, ED);
        ln_kernel<<<SQ, 256, 0, stream>>>(h, ln2_g + l * ED, ln2_b + l * ED, x);
        gemm_kernel<1, false><<<dim3(ID / 64, SQ / 64), 256, 0, stream>>>(
            x, cfc_w + 4 * lEE, cfc_b + (size_t)l * ID, nullptr, mbuf, SQ, ID, ED);
        gemm_kernel<0, true><<<dim3(ED / 64, SQ / 64), 256, 0, stream>>>(
            mbuf, mpw + 4 * lEE, mpb + (size_t)l * ED, h, h, SQ, ED, ID);
    }

    ln_kernel<<<SQ, 256, 0, stream>>>(h, lnf_g, lnf_b, x);
    lmhead_kernel<<<(NV + 3) / 4, 256, 0, stream>>>(x, wte, logit);
    probs_kernel<<<1, 256, 0, stream>>>(logit, out);
}

// Round 2
// 3763.888 us; speedup vs baseline: 3.5733x; 3.5733x over previous
//
#include <hip/hip_runtime.h>
#include <math.h>

#define SQ 1024
#define ED 1024
#define NH 16
#define HD 64
#define NL 12
#define ID 4096
#define NV 50257
#define EPS 1e-5f

typedef float f32x4 __attribute__((ext_vector_type(4)));
typedef short s16x8 __attribute__((ext_vector_type(8)));
typedef short s16x4 __attribute__((ext_vector_type(4)));

__device__ __forceinline__ short f2bf(float f) {
    union { float f; unsigned u; } c; c.f = f;
    unsigned u = c.u + 0x7fffu + ((c.u >> 16) & 1u);
    return (short)(u >> 16);
}
__device__ __forceinline__ float bf2f(short s) {
    union { unsigned u; float f; } c; c.u = ((unsigned)(unsigned short)s) << 16;
    return c.f;
}

// ---------------- embedding ----------------
__global__ void embed_kernel(const int* __restrict__ ids, const float* __restrict__ wte,
                             const float* __restrict__ wpe, float* __restrict__ h) {
    int s = blockIdx.x;
    int tok = ids[s];
    for (int e = threadIdx.x; e < ED; e += 256)
        h[(size_t)s * ED + e] = wte[(size_t)tok * ED + e] + wpe[(size_t)s * ED + e];
}

// ---------------- layernorm (f32 in, bf16 or f32 out) ----------------
template <bool BF>
__global__ void ln_kernel(const float* __restrict__ in, const float* __restrict__ g,
                          const float* __restrict__ b, void* __restrict__ outv) {
    int s = blockIdx.x;
    int tid = threadIdx.x;
    const float* row = in + (size_t)s * ED;
    __shared__ float red[256];
    float sum = 0.f;
    for (int e = tid; e < ED; e += 256) sum += row[e];
    red[tid] = sum; __syncthreads();
    for (int off = 128; off > 0; off >>= 1) { if (tid < off) red[tid] += red[tid + off]; __syncthreads(); }
    float mu = red[0] * (1.f / ED);
    __syncthreads();
    float vs = 0.f;
    for (int e = tid; e < ED; e += 256) { float d = row[e] - mu; vs += d * d; }
    red[tid] = vs; __syncthreads();
    for (int off = 128; off > 0; off >>= 1) { if (tid < off) red[tid] += red[tid + off]; __syncthreads(); }
    float rstd = rsqrtf(red[0] * (1.f / ED) + EPS);
    for (int e = tid; e < ED; e += 256) {
        float v = (row[e] - mu) * rstd * g[e] + b[e];
        if (BF) ((unsigned short*)outv)[(size_t)s * ED + e] = (unsigned short)f2bf(v);
        else    ((float*)outv)[(size_t)s * ED + e] = v;
    }
}

// ---------------- MFMA GEMM: C[M,N] = act(A_bf16[M,K] @ W_f32[N,K]^T + bias) (+res) ----------
// BM=128, BN in {128,64}, BK=32, 256 threads (4 waves as 2x2), 16x16x32 bf16 MFMA.
template <int BN, int ACT, bool RES, bool OUTBF>
__global__ __launch_bounds__(256) void mm_kernel(const unsigned short* __restrict__ A,
    const float* __restrict__ W, const float* __restrict__ bias,
    const float* __restrict__ res, void* __restrict__ Cout, int M, int N, int K) {
    constexpr int WNF = BN / 32;          // B-frags per wave
    __shared__ short As[128][32];
    __shared__ short Bs[BN][32];
    int tid = threadIdx.x;
    int m0 = blockIdx.y * 128, n0 = blockIdx.x * BN;
    int w = tid >> 6, l = tid & 63;
    int wm = w >> 1, wn = w & 1;
    int lg = l >> 4, lq = l & 15;
    f32x4 acc[4][WNF];
#pragma unroll
    for (int mi = 0; mi < 4; ++mi)
#pragma unroll
        for (int ni = 0; ni < WNF; ++ni) acc[mi][ni] = (f32x4){0.f, 0.f, 0.f, 0.f};

    for (int k0 = 0; k0 < K; k0 += 32) {
        // stage A (bf16): 128x32, 2 iters of 256 lanes x 8 elems
#pragma unroll
        for (int i = 0; i < 2; ++i) {
            int r = i * 64 + (tid >> 2), c = (tid & 3) * 8;
            *(s16x8*)&As[r][c] = *(const s16x8*)&A[(size_t)(m0 + r) * K + k0 + c];
        }
        // stage W (f32 -> bf16): BNx32, WNF iters of 256 lanes x 4 f32
#pragma unroll
        for (int i = 0; i < WNF; ++i) {
            int r = i * 32 + (tid >> 3), c = (tid & 7) * 4;
            f32x4 wv = *(const f32x4*)&W[(size_t)(n0 + r) * K + k0 + c];
            s16x4 bv;
#pragma unroll
            for (int j = 0; j < 4; ++j) bv[j] = f2bf(wv[j]);
            *(s16x4*)&Bs[r][c] = bv;
        }
        __syncthreads();
        s16x8 af[4], bfr[WNF];
#pragma unroll
        for (int mi = 0; mi < 4; ++mi)
            af[mi] = *(const s16x8*)&As[wm * 64 + mi * 16 + lq][lg * 8];
#pragma unroll
        for (int ni = 0; ni < WNF; ++ni)
            bfr[ni] = *(const s16x8*)&Bs[wn * (BN / 2) + ni * 16 + lq][lg * 8];
#pragma unroll
        for (int mi = 0; mi < 4; ++mi)
#pragma unroll
            for (int ni = 0; ni < WNF; ++ni)
                acc[mi][ni] = __builtin_amdgcn_mfma_f32_16x16x32_bf16(af[mi], bfr[ni], acc[mi][ni], 0, 0, 0);
        __syncthreads();
    }
    // epilogue: C/D layout row = 4*lg + r, col = lq (per 16x16 frag)
#pragma unroll
    for (int mi = 0; mi < 4; ++mi) {
#pragma unroll
        for (int ni = 0; ni < WNF; ++ni) {
            int col = n0 + wn * (BN / 2) + ni * 16 + lq;
            float bv = bias[col];
#pragma unroll
            for (int r = 0; r < 4; ++r) {
                int row = m0 + wm * 64 + mi * 16 + lg * 4 + r;
                float v = acc[mi][ni][r] + bv;
                if (ACT == 1) {
                    float x = v;
                    v = 0.5f * x * (1.f + tanhf(0.7978845608028654f * (x + 0.044715f * x * x * x)));
                }
                if (RES) v += res[(size_t)row * N + col];
                if (OUTBF) ((unsigned short*)Cout)[(size_t)row * N + col] = (unsigned short)f2bf(v);
                else       ((float*)Cout)[(size_t)row * N + col] = v;
            }
        }
    }
}

// ---------------- pack: qkv f32 -> Qb,Kb bf16 [h][s][64], VT bf16 [h][64][s], kc/vc f32 ----
__global__ __launch_bounds__(256) void pack_kernel(const float* __restrict__ qkv,
    unsigned short* __restrict__ Qb, unsigned short* __restrict__ Kb,
    unsigned short* __restrict__ VT, float* __restrict__ kc, float* __restrict__ vc) {
    __shared__ short Vs[64][66];
    int s0 = blockIdx.x * 64, h = blockIdx.y;
    int t = threadIdx.x;
#pragma unroll
    for (int i = 0; i < 16; ++i) {
        int e = i * 256 + t;
        int sl = e >> 6, d = e & 63;
        const float* base = &qkv[(size_t)(s0 + sl) * (3 * ED) + h * HD + d];
        float qv = base[0], kv = base[ED], vv = base[2 * ED];
        size_t o = ((size_t)h * SQ + s0 + sl) * HD + d;
        Qb[o] = (unsigned short)f2bf(qv);
        Kb[o] = (unsigned short)f2bf(kv);
        kc[o] = kv; vc[o] = vv;
        Vs[sl][d] = f2bf(vv);
    }
    __syncthreads();
#pragma unroll
    for (int i = 0; i < 16; ++i) {
        int e = i * 256 + t;
        int d = e >> 6, sl = e & 63;
        VT[((size_t)h * HD + d) * SQ + s0 + sl] = (unsigned short)Vs[sl][d];
    }
}

// ---------------- flash attention, MFMA, swapped-operand QK^T ----------------
// grid (16 strip-groups, NH heads), 4 waves/block, each wave owns a 16-row q-strip.
__global__ __launch_bounds__(256) void attn_kernel(
    const unsigned short* __restrict__ Qb, const unsigned short* __restrict__ Kb,
    const unsigned short* __restrict__ VT, const float* __restrict__ ab,
    unsigned short* __restrict__ ctxb) {
    __shared__ short Pt[4][16][32];       // per-wave P^T staging: [q'][k']
    int w = threadIdx.x >> 6, l = threadIdx.x & 63;
    int h = blockIdx.y;
    int q0 = (blockIdx.x * 4 + w) * 16;
    int lg = l >> 4, lq = l & 15;
    const unsigned short* Qh = Qb + (size_t)h * SQ * HD;
    const unsigned short* Kh = Kb + (size_t)h * SQ * HD;
    const unsigned short* VTh = VT + (size_t)h * HD * SQ;

    // Q^T B-frags (hoisted): lane needs Q[q0+lq][dh*32 + lg*8 + j]
    s16x8 qf[2];
    qf[0] = *(const s16x8*)&Qh[(size_t)(q0 + lq) * HD + lg * 8];
    qf[1] = *(const s16x8*)&Qh[(size_t)(q0 + lq) * HD + 32 + lg * 8];

    f32x4 ctx[4];
#pragma unroll
    for (int dt = 0; dt < 4; ++dt) ctx[dt] = (f32x4){0.f, 0.f, 0.f, 0.f};
    float m = -1e30f, lsum = 0.f;
    int ntile = (q0 + 15) / 32 + 1;

    for (int t = 0; t < ntile; ++t) {
        int k0 = t * 32;
        f32x4 sf[2];
        sf[0] = (f32x4){0.f, 0.f, 0.f, 0.f};
        sf[1] = (f32x4){0.f, 0.f, 0.f, 0.f};
#pragma unroll
        for (int kh = 0; kh < 2; ++kh)
#pragma unroll
            for (int dh = 0; dh < 2; ++dh) {
                s16x8 kf = *(const s16x8*)&Kh[(size_t)(k0 + kh * 16 + lq) * HD + dh * 32 + lg * 8];
                sf[kh] = __builtin_amdgcn_mfma_f32_16x16x32_bf16(kf, qf[dh], sf[kh], 0, 0, 0);
            }
        // S^T frag: lane holds k' = kh*16 + 4*lg + r, q' = lq
        float s8[8];
        float tmax = -1e30f;
#pragma unroll
        for (int kh = 0; kh < 2; ++kh) {
            f32x4 abv = *(const f32x4*)&ab[(size_t)(q0 + lq) * SQ + k0 + kh * 16 + lg * 4];
#pragma unroll
            for (int r = 0; r < 4; ++r) {
                int kk = k0 + kh * 16 + lg * 4 + r;
                float v = sf[kh][r] * 0.125f + abv[r];
                if (kk > q0 + lq) v = -1e9f;
                s8[kh * 4 + r] = v;
                tmax = fmaxf(tmax, v);
            }
        }
        tmax = fmaxf(tmax, __shfl_xor(tmax, 16));
        tmax = fmaxf(tmax, __shfl_xor(tmax, 32));
        float mnew = fmaxf(m, tmax);
        float sc = __expf(m - mnew);
        m = mnew;
        lsum *= sc;
#pragma unroll
        for (int kh = 0; kh < 2; ++kh) {
            s16x4 pb;
#pragma unroll
            for (int r = 0; r < 4; ++r) {
                float p = __expf(s8[kh * 4 + r] - mnew);
                lsum += p;
                pb[r] = f2bf(p);
            }
            *(s16x4*)&Pt[w][lq][kh * 16 + lg * 4] = pb;
        }
#pragma unroll
        for (int dt = 0; dt < 4; ++dt) ctx[dt] *= sc;
        // PV: A = V^T[d][k] (global, contiguous), B = P[k][q] (LDS b128)
        s16x8 pf = *(const s16x8*)&Pt[w][lq][lg * 8];
#pragma unroll
        for (int dt = 0; dt < 4; ++dt) {
            s16x8 vf = *(const s16x8*)&VTh[(size_t)(dt * 16 + lq) * SQ + k0 + lg * 8];
            ctx[dt] = __builtin_amdgcn_mfma_f32_16x16x32_bf16(vf, pf, ctx[dt], 0, 0, 0);
        }
    }
    float tot = lsum + __shfl_xor(lsum, 16);
    tot += __shfl_xor(tot, 32);
    float inv = 1.f / tot;
#pragma unroll
    for (int dt = 0; dt < 4; ++dt) {
        s16x4 ov;
#pragma unroll
        for (int r = 0; r < 4; ++r) ov[r] = f2bf(ctx[dt][r] * inv);
        *(s16x4*)&ctxb[(size_t)(q0 + lq) * ED + h * HD + dt * 16 + lg * 4] = ov;
    }
}

// ---------------- lm head matvec (f32 x, f32 wte) ----------------
__global__ void lmhead_kernel(const float* __restrict__ x, const float* __restrict__ wte,
                              float* __restrict__ logits) {
    __shared__ float xs[ED];
    int tid = threadIdx.x;
    for (int i = tid; i < ED; i += 256) xs[i] = x[(size_t)(SQ - 1) * ED + i];
    __syncthreads();
    int wave = tid >> 6, lane = tid & 63;
    int v = blockIdx.x * 4 + wave;
    if (v >= NV) return;
    const float* wr = wte + (size_t)v * ED;
    float acc = 0.f;
#pragma unroll 4
    for (int t = 0; t < ED / 64; ++t) acc = fmaf(xs[lane + t * 64], wr[lane + t * 64], acc);
    for (int off = 32; off > 0; off >>= 1) acc += __shfl_down(acc, off, 64);
    if (lane == 0) logits[v] = acc;
}

// ---------------- softmax + argmax over V ----------------
__global__ void probs_kernel(const float* __restrict__ logits, float* __restrict__ out) {
    __shared__ float red[256];
    __shared__ int redi[256];
    int tid = threadIdx.x;
    float lmax = -1e30f; int li = 0;
    for (int v = tid; v < NV; v += 256) {
        float x = logits[v];
        if (x > lmax) { lmax = x; li = v; }
    }
    red[tid] = lmax; redi[tid] = li; __syncthreads();
    for (int off = 128; off > 0; off >>= 1) {
        if (tid < off) {
            float a = red[tid], b = red[tid + off];
            if (b > a || (b == a && redi[tid + off] < redi[tid])) { red[tid] = b; redi[tid] = redi[tid + off]; }
        }
        __syncthreads();
    }
    float mx = red[0]; int amax = redi[0];
    __syncthreads();
    float lsum = 0.f;
    for (int v = tid; v < NV; v += 256) lsum += expf(logits[v] - mx);
    red[tid] = lsum; __syncthreads();
    for (int off = 128; off > 0; off >>= 1) { if (tid < off) red[tid] += red[tid + off]; __syncthreads(); }
    float inv = 1.f / red[0];
    for (int v = tid; v < NV; v += 256) out[1 + v] = expf(logits[v] - mx) * inv;
    if (tid == 0) out[0] = (float)amax;
}

extern "C" void kernel_launch(void* const* d_in, const int* in_sizes, int n_in,
                              void* d_out, int out_size, void* d_ws, size_t ws_size,
                              hipStream_t stream) {
    const int*   ids      = (const int*)d_in[0];
    const float* wte      = (const float*)d_in[1];
    const float* wpe      = (const float*)d_in[2];
    const float* ln1_g    = (const float*)d_in[3];
    const float* ln1_b    = (const float*)d_in[4];
    const float* c_attn_w = (const float*)d_in[5];
    const float* c_attn_b = (const float*)d_in[6];
    const float* ab       = (const float*)d_in[7];
    const float* apw      = (const float*)d_in[8];
    const float* apb      = (const float*)d_in[9];
    const float* ln2_g    = (const float*)d_in[10];
    const float* ln2_b    = (const float*)d_in[11];
    const float* cfc_w    = (const float*)d_in[12];
    const float* cfc_b    = (const float*)d_in[13];
    const float* mpw      = (const float*)d_in[14];
    const float* mpb      = (const float*)d_in[15];
    const float* lnf_g    = (const float*)d_in[16];
    const float* lnf_b    = (const float*)d_in[17];

    float* out = (float*)d_out;
    float* kc  = out + 1 + NV;
    float* vc  = kc + (size_t)NL * NH * SQ * HD;

    char* w8 = (char*)d_ws;
    float*          h    = (float*)(w8);                         // 4 MB
    unsigned short* xb   = (unsigned short*)(w8 + (4u << 20));   // 2 MB
    float*          qkv  = (float*)(w8 + (6u << 20));            // 12 MB (reused as mbuf/xf)
    unsigned short* mbuf = (unsigned short*)qkv;
    float*          xf   = qkv;
    unsigned short* Qb   = (unsigned short*)(w8 + (18u << 20));  // 2 MB
    unsigned short* Kb   = (unsigned short*)(w8 + (20u << 20));  // 2 MB
    unsigned short* VT   = (unsigned short*)(w8 + (22u << 20));  // 2 MB
    unsigned short* ctxb = (unsigned short*)(w8 + (24u << 20));  // 2 MB
    float*          logi = (float*)(w8 + (26u << 20));           // 0.2 MB

    embed_kernel<<<SQ, 256, 0, stream>>>(ids, wte, wpe, h);

    for (int l = 0; l < NL; ++l) {
        const size_t lEE = (size_t)l * ED * ED;
        float* kcl = kc + (size_t)l * NH * SQ * HD;
        float* vcl = vc + (size_t)l * NH * SQ * HD;

        ln_kernel<true><<<SQ, 256, 0, stream>>>(h, ln1_g + l * ED, ln1_b + l * ED, xb);
        mm_kernel<128, 0, false, false><<<dim3(3 * ED / 128, SQ / 128), 256, 0, stream>>>(
            xb, c_attn_w + 3 * lEE, c_attn_b + (size_t)l * 3 * ED, nullptr, qkv, SQ, 3 * ED, ED);
        pack_kernel<<<dim3(SQ / 64, NH), 256, 0, stream>>>(qkv, Qb, Kb, VT, kcl, vcl);
        attn_kernel<<<dim3(SQ / 64, NH), 256, 0, stream>>>(Qb, Kb, VT,
            ab + (size_t)l * SQ * SQ, ctxb);
        mm_kernel<64, 0, true, false><<<dim3(ED / 64, SQ / 128), 256, 0, stream>>>(
            ctxb, apw + lEE, apb + (size_t)l * ED, h, h, SQ, ED, ED);
        ln_kernel<true><<<SQ, 256, 0, stream>>>(h, ln2_g + l * ED, ln2_b + l * ED, xb);
        mm_kernel<128, 1, false, true><<<dim3(ID / 128, SQ / 128), 256, 0, stream>>>(
            xb, cfc_w + 4 * lEE, cfc_b + (size_t)l * ID, nullptr, mbuf, SQ, ID, ED);
        mm_kernel<64, 0, true, false><<<dim3(ED / 64, SQ / 128), 256, 0, stream>>>(
            mbuf, mpw + 4 * lEE, mpb + (size_t)l * ED, h, h, SQ, ED, ID);
    }

    ln_kernel<false><<<SQ, 256, 0, stream>>>(h, lnf_g, lnf_b, xf);
    lmhead_kernel<<<(NV + 3) / 4, 256, 0, stream>>>(xf, wte, logi);
    probs_kernel<<<1, 256, 0, stream>>>(logi, out);
}